// Round 14
// baseline (756.563 us; speedup 1.0000x reference)
//
#include <hip/hip_runtime.h>

// ---------------------------------------------------------------------------
// RNN-KAN forward.  B=1024, Tx=64, IN0=256, H=512, TY=16, coeff=8.
// Output: y_pred (1024*16 f32) then h_all (1024*80*512 f32), flat.
// R14 = R13 with (1) GEMM single-barrier double-buffered pipeline and
// (2) rnn signal atomic RELEASE->RELAXED (ordering already via vmcnt(0) on
// write-through stores; agent RELEASE may emit per-step L2 writeback).
// GEMM ledger: 128x512 1-blk/CU ~270us; 128x128 VALU-bound 588us;
// (512,6) spill 890us; 128x256 2-barrier ~270us.
// ---------------------------------------------------------------------------

using s16x8 = __attribute__((ext_vector_type(8))) short;
using u16x8 = __attribute__((ext_vector_type(8))) unsigned short;
using f32x4 = __attribute__((ext_vector_type(4))) float;
using u32x2 = __attribute__((ext_vector_type(2))) unsigned;

#define HALL_TSTRIDE 512
#define HALL_BSTRIDE (80 * 512)

__device__ __forceinline__ unsigned short f2bf(float f) {
  unsigned u = __builtin_bit_cast(unsigned, f);
  u += 0x7fffu + ((u >> 16) & 1u);   // round-to-nearest-even
  return (unsigned short)(u >> 16);
}
__device__ __forceinline__ float bf2f(unsigned short h) {
  unsigned u = ((unsigned)h) << 16;
  return __builtin_bit_cast(float, u);
}
__device__ __forceinline__ float silu(float x) {
  return x / (1.f + __expf(-x));
}
__device__ __forceinline__ float tanh_fast(float x) {
  float e2 = __expf(2.f * x);                    // inf/0 saturate correctly
  return 1.f - 2.f * __builtin_amdgcn_rcpf(e2 + 1.f);
}

// 8 cubic B-spline basis values on the uniform 12-knot grid.
__device__ __forceinline__ void basis8_f32(float xv, float g0, float invh, float* out) {
  float u = (xv - g0) * invh;
  float fs = floorf(u);
  int s = (int)fs;
  float r = u - fs;
  float omr = 1.f - r;
  float r2 = r * r, r3 = r2 * r;
  float n0 = (1.f / 6.f) * omr * omr * omr;
  float n1 = (1.f / 6.f) * (3.f * r3 - 6.f * r2 + 4.f);
  float n2 = (1.f / 6.f) * (-3.f * r3 + 3.f * r2 + 3.f * r + 1.f);
  float n3 = (1.f / 6.f) * r3;
#pragma unroll
  for (int j = 0; j < 8; ++j) {
    int d = s - j;
    out[j] = (d == 0) ? n3 : (d == 1) ? n2 : (d == 2) ? n1 : (d == 3) ? n0 : 0.f;
  }
}

__device__ __forceinline__ u16x8 basis8_bf16(float xv, float g0, float invh) {
  float t[8];
  basis8_f32(xv, g0, invh, t);
  u16x8 o;
#pragma unroll
  for (int j = 0; j < 8; ++j) o[j] = f2bf(t[j]);
  return o;
}

// ---------------------------------------------------------------------------
// Prep kernels
// ---------------------------------------------------------------------------
// Waug2: tiled + swizzled B-panel image for global_load_lds.
// Region per kstep ks (64 k): 512 rows x 64 shorts (128 B/row = 8 slots of 16B).
// Logical slot q = (k>>3)&7 stored at physical slot p = q ^ (o&7).
__global__ __launch_bounds__(256) void prep_waug2(const float* __restrict__ bw,
                                                  const float* __restrict__ sw,
                                                  const float* __restrict__ sc,
                                                  unsigned short* __restrict__ Waug2) {
  int o = blockIdx.x;
  for (int k = threadIdx.x; k < 2304; k += 256) {
    float v;
    if (k < 256) {
      v = bw[o * 256 + k];
    } else {
      int idx = k - 256;
      int i = idx >> 3, g = idx & 7;
      v = sw[(o * 256 + i) * 8 + g] * sc[o * 256 + i];
    }
    int ks = k >> 6;
    int q = (k >> 3) & 7;
    int p = q ^ (o & 7);
    int e = k & 7;
    Waug2[(long)ks * 32768 + o * 64 + p * 8 + e] = f2bf(v);
  }
}

__global__ __launch_bounds__(256) void prep_whh(const float* __restrict__ w,
                                                unsigned short* __restrict__ hi,
                                                unsigned short* __restrict__ lo) {
  for (int i = blockIdx.x * 256 + threadIdx.x; i < 512 * 512; i += gridDim.x * 256) {
    float v = w[i];
    unsigned short h = f2bf(v);
    hi[i] = h;
    lo[i] = f2bf(v - bf2f(h));
  }
}

// i2h for x==0: parallel (one block per output, coalesced, LDS tree reduce).
__global__ __launch_bounds__(256) void prep_i2hz(const float* __restrict__ sw,
                                                 const float* __restrict__ sc,
                                                 const float* __restrict__ grd,
                                                 float* __restrict__ i2hz,
                                                 unsigned* __restrict__ cnt) {
  __shared__ float red[256];
  const int o = blockIdx.x;
  const int t = threadIdx.x;
  if (o == 0) {
    for (int i = t; i < 64 * 32; i += 256) cnt[i] = 0u;
  }
  float g0 = grd[0];
  float invh = 1.f / (grd[1] - grd[0]);
  float bs[8];
  basis8_f32(0.f, g0, invh, bs);
  const float* swrow = sw + ((long)o * 256 + t) * 8;
  float a = 0.f;
#pragma unroll
  for (int j = 0; j < 8; ++j) a += bs[j] * swrow[j];
  red[t] = a * sc[o * 256 + t];
  __syncthreads();
  for (int w = 128; w > 0; w >>= 1) {
    if (t < w) red[t] += red[t + w];
    __syncthreads();
  }
  if (t == 0) i2hz[o] = red[0];
}

// ---------------------------------------------------------------------------
// Phase A: i2h GEMM.  C(65536 x 512) = A_aug(65536 x 2304) @ W_aug^T.
// R14: single-barrier double-buffered pipeline.  1024 blocks x 512 threads;
// tile 128m x 256n; LDS 96KB (Bs 2x32K + As 2x16K); one __syncthreads per
// K-step.  Per iter: barrier -> ds_read ALL frags to regs -> issue DMA(ks+1)
// + A-write(ks+1) into other buffer -> computeA(ks+2) -> MFMA on regs.
// DMA has the whole MFMA phase to complete before the next barrier drains it.
// ---------------------------------------------------------------------------
__global__ __launch_bounds__(512, 2) void kan_i2h_gemm(const float* __restrict__ x,
                                                       const float* __restrict__ grd,
                                                       const unsigned short* __restrict__ Waug2,
                                                       float* __restrict__ hall) {
  __shared__ __align__(128) short Bs[2][256 * 64];   // 2 x 32 KB
  __shared__ __align__(128) short As[2][128 * 64];   // 2 x 16 KB

  const int bid = blockIdx.x;
  const int m0 = (bid >> 1) * 128;
  const int n0 = (bid & 1) * 256;
  const int tid = threadIdx.x;
  const int lane = tid & 63, wave = tid >> 6;   // 8 waves
  const int wr = wave >> 2, wc = wave & 3;      // 2 x 4
  const int colg = lane & 15, kgrp = lane >> 4;

  float g0 = grd[0];
  float invh = 1.f / (grd[1] - grd[0]);

  f32x4 acc[4][4] = {};

  const int arow = tid >> 2, apart = tid & 3;   // A: 128 rows x 4 parts x 16k
  const float* xrow = x + (long)(m0 + arow) * 256;
  const int aswz = arow & 7;
  const int aoff0 = arow * 128 + ((apart * 2) ^ aswz) * 16;
  const int aoff1 = arow * 128 + ((apart * 2 + 1) ^ aswz) * 16;

  // A-compute for one kstep into registers (16 k per thread).
  auto computeA = [&](int ks, u16x8& d0, u16x8& d1) {
    int kA = ks * 64 + apart * 16;
    if (ks < 4) {
      const float* xs = xrow + kA;
      f32x4 v0 = *(const f32x4*)(xs);
      f32x4 v1 = *(const f32x4*)(xs + 4);
      f32x4 v2 = *(const f32x4*)(xs + 8);
      f32x4 v3 = *(const f32x4*)(xs + 12);
#pragma unroll
      for (int e = 0; e < 4; ++e) {
        d0[e] = f2bf(silu(v0[e]));
        d0[e + 4] = f2bf(silu(v1[e]));
        d1[e] = f2bf(silu(v2[e]));
        d1[e + 4] = f2bf(silu(v3[e]));
      }
    } else {
      int i0 = (kA - 256) >> 3;
      d0 = basis8_bf16(xrow[i0], g0, invh);
      d1 = basis8_bf16(xrow[i0 + 1], g0, invh);
    }
  };

  // B DMA for kstep ks into Bs[ks&1] (linear copy; content pre-swizzled).
  auto stageB = [&](int ks) {
    const char* bsrc = (const char*)Waug2 + (long)ks * 65536 + n0 * 128 +
                       wave * 4096 + lane * 16;
    char* bdst = (char*)Bs[ks & 1] + wave * 4096;
#pragma unroll
    for (int i = 0; i < 4; ++i)
      __builtin_amdgcn_global_load_lds(
          (const __attribute__((address_space(1))) unsigned int*)(bsrc + i * 1024),
          (__attribute__((address_space(3))) unsigned int*)(bdst + i * 1024), 16, 0, 0);
  };

  // prologue: fill buffer 0, pipeline regs for kstep 1
  u16x8 ar0, ar1;
  computeA(0, ar0, ar1);
  stageB(0);
  *(u16x8*)((char*)As[0] + aoff0) = ar0;
  *(u16x8*)((char*)As[0] + aoff1) = ar1;
  computeA(1, ar0, ar1);

  for (int ks = 0; ks < 36; ++ks) {
    __syncthreads();   // drains vmcnt+lgkm: B[ks] + A[ks] ready in buf ks&1
    const char* asb = (const char*)As[ks & 1];
    const char* bsb = (const char*)Bs[ks & 1];
    s16x8 a[2][4], b[2][4];
#pragma unroll
    for (int kk = 0; kk < 2; ++kk) {
      const int q = kk * 4 + kgrp;
#pragma unroll
      for (int i = 0; i < 4; ++i) {
        int ra = wr * 64 + i * 16 + colg;
        a[kk][i] = *(const s16x8*)(asb + ra * 128 + (q ^ (ra & 7)) * 16);
      }
#pragma unroll
      for (int j = 0; j < 4; ++j) {
        int rb = wc * 64 + j * 16 + colg;   // local row; n0%8==0 -> rb&7 == o&7
        b[kk][j] = *(const s16x8*)(bsb + rb * 128 + (q ^ (rb & 7)) * 16);
      }
    }
    // stage next tile into the other buffer (overlaps MFMA below)
    if (ks + 1 < 36) {
      stageB(ks + 1);
      char* asn = (char*)As[(ks + 1) & 1];
      *(u16x8*)(asn + aoff0) = ar0;
      *(u16x8*)(asn + aoff1) = ar1;
      if (ks + 2 < 36) computeA(ks + 2, ar0, ar1);
    }
#pragma unroll
    for (int kk = 0; kk < 2; ++kk)
#pragma unroll
      for (int i = 0; i < 4; ++i)
#pragma unroll
        for (int j = 0; j < 4; ++j)
          acc[i][j] = __builtin_amdgcn_mfma_f32_16x16x32_bf16(a[kk][i], b[kk][j],
                                                              acc[i][j], 0, 0, 0);
  }

  const int c0 = n0 + wc * 64;
#pragma unroll
  for (int i = 0; i < 4; ++i) {
    int mbase = m0 + wr * 64 + i * 16 + (kgrp << 2);
#pragma unroll
    for (int r = 0; r < 4; ++r) {
      int m = mbase + r;
      int bb = m >> 6, tt = m & 63;
      float* orow = hall + (long)bb * HALL_BSTRIDE + (long)tt * HALL_TSTRIDE + c0;
#pragma unroll
      for (int j = 0; j < 4; ++j) orow[j * 16 + colg] = acc[i][j][r];
    }
  }
}

// ---------------------------------------------------------------------------
// Phase B: VGPR-pinned-weight recurrence — R6/R8/R10 structure (~410us).
// 256 blocks x 512 threads (1 block/CU), block = 16 batch rows x 128 cols,
// 8 waves x 16 cols, weights pinned via asm loads, 4 siblings/group per XCD.
// R14 change: signal atomic is RELAXED (was RELEASE).  Ordering argument:
// the h stores are sc0sc1 (write-through to the coherent point) and are
// fully drained by vmcnt(0) BEFORE the atomic issues; observers poll with
// relaxed loads and read data with sc0sc1 loads that bypass local caches.
// RELEASE at agent scope may emit an L2 writeback per step — pure overhead.
// Do NOT: 4-wave blocks (R9 -2.3x), nt-store exchange (R7 -1.8x),
// LDS-stream weights (R3 -1.3x).
// ---------------------------------------------------------------------------
__device__ __forceinline__ void pack_write_h(f32x4 v, int rr, int c16,
                                             char* hHb, char* hLb) {
  unsigned h0 = f2bf(v[0]), h1 = f2bf(v[1]), h2 = f2bf(v[2]), h3 = f2bf(v[3]);
  unsigned l0 = f2bf(v[0] - bf2f((unsigned short)h0));
  unsigned l1 = f2bf(v[1] - bf2f((unsigned short)h1));
  unsigned l2 = f2bf(v[2] - bf2f((unsigned short)h2));
  unsigned l3 = f2bf(v[3] - bf2f((unsigned short)h3));
  u32x2 hw, lw;
  hw[0] = h0 | (h1 << 16); hw[1] = h2 | (h3 << 16);
  lw[0] = l0 | (l1 << 16); lw[1] = l2 | (l3 << 16);
  int byte = (rr * 1024 + c16 * 8) ^ ((rr & 7) << 4);
  *(u32x2*)(hHb + byte) = hw;
  *(u32x2*)(hLb + byte) = lw;
}

__global__ __launch_bounds__(512, 2) void rnn_persist(
    const unsigned short* __restrict__ WhhHi,
    const unsigned short* __restrict__ WhhLo,
    const float* __restrict__ i2hz,
    const float* __restrict__ h2hb,
    const float* __restrict__ h0,
    float* __restrict__ hall,
    unsigned* __restrict__ cnt) {
  __shared__ __align__(16) char hHb[16 * 1024];
  __shared__ __align__(16) char hLb[16 * 1024];

  const int tid = threadIdx.x;
  const int lane = tid & 63;
  const int wave = tid >> 6;            // 0..7
  const int bid = blockIdx.x;
  // XCD-local grouping: the 4 col-siblings of a batch-group share bid%8
  const int xcd = bid & 7;              // XCD (round-robin dispatch)
  const int j = bid >> 3;               // 0..31
  const int cg = j & 3;                 // col-group
  const int g = xcd * 8 + (j >> 2);     // batch-group 0..63
  const int m0 = g * 16;                // batch rows
  const int colg = lane & 15;
  const int kgrp = lane >> 4;           // 0..3
  const int o = cg * 128 + wave * 16 + colg;   // this lane's output col
  const int aswz = (colg & 7) << 4;

  // ---- pin this wave's weight slice in VGPRs (asm: not rematerializable) --
  s16x8 wh[16], wl[16];
#pragma unroll
  for (int kk = 0; kk < 16; ++kk) {
    const unsigned short* ph = WhhHi + (long)o * 512 + kk * 32 + kgrp * 8;
    const unsigned short* pl = WhhLo + (long)o * 512 + kk * 32 + kgrp * 8;
    asm volatile("global_load_dwordx4 %0, %1, off" : "=v"(wh[kk]) : "v"(ph));
    asm volatile("global_load_dwordx4 %0, %1, off" : "=v"(wl[kk]) : "v"(pl));
  }
  const float bias = h2hb[o];
  const float i2z = i2hz[o];
  asm volatile("s_waitcnt vmcnt(0)" ::: "memory");
  __builtin_amdgcn_sched_barrier(0);

  // ---- prologue: h0 -> LDS (hi/lo, swizzled) ----
  {
    const int rr = tid >> 5, cc = tid & 31;
#pragma unroll
    for (int jj = 0; jj < 4; ++jj) {
      int c16 = cc + jj * 32;
      f32x4 v = *(const f32x4*)(h0 + (long)(m0 + rr) * 512 + c16 * 4);
      pack_write_h(v, rr, c16, hHb, hLb);
    }
  }
  __syncthreads();

  for (int T = 0; T < 80; ++T) {
    // issue i2h coherent loads early (land under MFMA loop)
    float i2v[4];
    if (T < 64) {
#pragma unroll
      for (int r = 0; r < 4; ++r) {
        const float* p = hall + (long)(m0 + kgrp * 4 + r) * HALL_BSTRIDE +
                         (long)T * HALL_TSTRIDE + o;
        asm volatile("global_load_dword %0, %1, off sc0 sc1" : "=v"(i2v[r]) : "v"(p));
      }
    }

    f32x4 aA = {}, aB = {}, aC = {};
#pragma unroll
    for (int kk = 0; kk < 16; ++kk) {
      int abyte = (colg * 1024 + kk * 64 + kgrp * 16) ^ aswz;
      s16x8 ah = *(const s16x8*)(hHb + abyte);
      s16x8 al = *(const s16x8*)(hLb + abyte);
      aA = __builtin_amdgcn_mfma_f32_16x16x32_bf16(ah, wh[kk], aA, 0, 0, 0);
      aB = __builtin_amdgcn_mfma_f32_16x16x32_bf16(ah, wl[kk], aB, 0, 0, 0);
      aC = __builtin_amdgcn_mfma_f32_16x16x32_bf16(al, wh[kk], aC, 0, 0, 0);
    }

    if (T < 64) {
      asm volatile("s_waitcnt vmcnt(0)" ::: "memory");
      __builtin_amdgcn_sched_barrier(0);
    } else {
#pragma unroll
      for (int r = 0; r < 4; ++r) i2v[r] = i2z;
    }

    // epilogue: tanh + coherent store of h into hall (the exchange medium)
#pragma unroll
    for (int r = 0; r < 4; ++r) {
      float pre = aA[r] + aB[r] + aC[r] + i2v[r] + bias;
      float h = tanh_fast(pre);
      float* p = hall + (long)(m0 + kgrp * 4 + r) * HALL_BSTRIDE +
                 (long)T * HALL_TSTRIDE + o;
      asm volatile("global_store_dword %0, %1, off sc0 sc1" :: "v"(p), "v"(h) : "memory");
    }

    if (T == 79) break;

    asm volatile("s_waitcnt vmcnt(0)" ::: "memory");
    __syncthreads();                       // all waves' stores complete
    if (tid == 0) {
      __hip_atomic_fetch_add(&cnt[g * 32], 1u, __ATOMIC_RELAXED,
                             __HIP_MEMORY_SCOPE_AGENT);
      unsigned tgt = 4u * (unsigned)(T + 1);
      while (__hip_atomic_load(&cnt[g * 32], __ATOMIC_RELAXED,
                               __HIP_MEMORY_SCOPE_AGENT) < tgt)
        __builtin_amdgcn_s_sleep(2);
    }
    __syncthreads();

    // A-refill: coherent loads of h_T (16 rows x 512) -> LDS hi/lo
    {
      const int rr = tid >> 5, cc = tid & 31;
      const float* src = hall + (long)(m0 + rr) * HALL_BSTRIDE + (long)T * HALL_TSTRIDE;
      f32x4 v[4];
#pragma unroll
      for (int jj = 0; jj < 4; ++jj) {
        const float* p = src + (cc + jj * 32) * 4;
        asm volatile("global_load_dwordx4 %0, %1, off sc0 sc1" : "=v"(v[jj]) : "v"(p));
      }
      asm volatile("s_waitcnt vmcnt(0)" ::: "memory");
      __builtin_amdgcn_sched_barrier(0);
#pragma unroll
      for (int jj = 0; jj < 4; ++jj) pack_write_h(v[jj], rr, cc + jj * 32, hHb, hLb);
    }
    __syncthreads();
  }
}

// ---------------------------------------------------------------------------
// y_pred[b][ty] = dot(h_all[b][64+ty][:], fc_w) + fc_b   (one wave per (b,ty))
// ---------------------------------------------------------------------------
__global__ __launch_bounds__(256) void y_final(const float* __restrict__ hall,
                                               const float* __restrict__ fcw,
                                               const float* __restrict__ fcb,
                                               float* __restrict__ y) {
  int gw = (blockIdx.x * 256 + threadIdx.x) >> 6;
  int lane = threadIdx.x & 63;
  int bb = gw >> 4, ty = gw & 15;
  const float* hrow = hall + (long)bb * HALL_BSTRIDE + (long)(64 + ty) * HALL_TSTRIDE;
  float s = 0.f;
#pragma unroll
  for (int c = 0; c < 8; ++c) s += hrow[lane + c * 64] * fcw[lane + c * 64];
#pragma unroll
  for (int off = 32; off > 0; off >>= 1) s += __shfl_xor(s, off);
  if (lane == 0) y[bb * 16 + ty] = s + fcb[0];
}

// ---------------------------------------------------------------------------
extern "C" void kernel_launch(void* const* d_in, const int* in_sizes, int n_in,
                              void* d_out, int out_size, void* d_ws, size_t ws_size,
                              hipStream_t stream) {
  (void)in_sizes; (void)n_in; (void)out_size; (void)ws_size;
  const float* x   = (const float*)d_in[0];
  const float* h0  = (const float*)d_in[1];
  const float* grd = (const float*)d_in[2];
  const float* bw  = (const float*)d_in[3];
  const float* sw  = (const float*)d_in[4];
  const float* sc  = (const float*)d_in[5];
  const float* whh = (const float*)d_in[6];
  const float* hbb = (const float*)d_in[7];
  const float* fcw = (const float*)d_in[8];
  const float* fcb = (const float*)d_in[9];

  float* out = (float*)d_out;
  float* ypred = out;
  float* hall = out + 1024 * 16;

  char* ws = (char*)d_ws;
  unsigned short* Waug2 = (unsigned short*)(ws);                 // 2359296 B
  unsigned short* WhhHi = (unsigned short*)(ws + 2359296);       // 524288 B
  unsigned short* WhhLo = (unsigned short*)(ws + 2883584);       // 524288 B
  float*          i2hz  = (float*)(ws + 3407872);                // 2048 B
  unsigned*       cnt   = (unsigned*)(ws + 3409920);             // 8192 B

  prep_waug2<<<512, 256, 0, stream>>>(bw, sw, sc, Waug2);
  prep_whh<<<512, 256, 0, stream>>>(whh, WhhHi, WhhLo);
  prep_i2hz<<<512, 256, 0, stream>>>(sw, sc, grd, i2hz, cnt);
  kan_i2h_gemm<<<1024, 512, 0, stream>>>(x, grd, Waug2, hall);
  rnn_persist<<<256, 512, 0, stream>>>(WhhHi, WhhLo, i2hz, hbb, h0, hall, cnt);
  y_final<<<4096, 256, 0, stream>>>(hall, fcw, fcb, ypred);
}

// Round 16
// 594.839 us; speedup vs baseline: 1.2719x; 1.2719x over previous
//
#include <hip/hip_runtime.h>

// ---------------------------------------------------------------------------
// RNN-KAN forward.  B=1024, Tx=64, IN0=256, H=512, TY=16, coeff=8.
// Output: y_pred (1024*16 f32) then h_all (1024*80*512 f32), flat.
// R16 = R13 (proven 716us; ==R10 712 within noise) + rnn own-col LDS
// shortcut (epilogue writes own 128 cols to LDS after the post-store
// barrier; refill skips them -> 25% less gated L2 reload).
// CLOSED LEVERS (ledger):
//  - fusion/overlap: BLOCKED — rnn holds ~230 unified VGPRs -> 8 waves/CU
//    -> 1 block/CU; rnn-first fused grid starved GEMM -> R15 600s hang.
//  - GEMM geometry: 128x512 ~270us == 128x256 2-barrier == +pipelined-A;
//    128x128 VALU-bound (588); (512,6) spills (890); 96KB dbuf 1blk/CU (511).
//  - rnn: don't split waves (R9 -2.3x), don't nt-store exchange (R7 -1.8x),
//    don't LDS-stream weights (R3 -1.3x), don't grid-barrier+fence (R1).
// ---------------------------------------------------------------------------

using s16x8 = __attribute__((ext_vector_type(8))) short;
using u16x8 = __attribute__((ext_vector_type(8))) unsigned short;
using f32x4 = __attribute__((ext_vector_type(4))) float;
using u32x2 = __attribute__((ext_vector_type(2))) unsigned;

#define HALL_TSTRIDE 512
#define HALL_BSTRIDE (80 * 512)

__device__ __forceinline__ unsigned short f2bf(float f) {
  unsigned u = __builtin_bit_cast(unsigned, f);
  u += 0x7fffu + ((u >> 16) & 1u);   // round-to-nearest-even
  return (unsigned short)(u >> 16);
}
__device__ __forceinline__ float bf2f(unsigned short h) {
  unsigned u = ((unsigned)h) << 16;
  return __builtin_bit_cast(float, u);
}
__device__ __forceinline__ float silu(float x) {
  return x / (1.f + __expf(-x));
}
__device__ __forceinline__ float tanh_fast(float x) {
  float e2 = __expf(2.f * x);                    // inf/0 saturate correctly
  return 1.f - 2.f * __builtin_amdgcn_rcpf(e2 + 1.f);
}

// 8 cubic B-spline basis values on the uniform 12-knot grid.
__device__ __forceinline__ void basis8_f32(float xv, float g0, float invh, float* out) {
  float u = (xv - g0) * invh;
  float fs = floorf(u);
  int s = (int)fs;
  float r = u - fs;
  float omr = 1.f - r;
  float r2 = r * r, r3 = r2 * r;
  float n0 = (1.f / 6.f) * omr * omr * omr;
  float n1 = (1.f / 6.f) * (3.f * r3 - 6.f * r2 + 4.f);
  float n2 = (1.f / 6.f) * (-3.f * r3 + 3.f * r2 + 3.f * r + 1.f);
  float n3 = (1.f / 6.f) * r3;
#pragma unroll
  for (int j = 0; j < 8; ++j) {
    int d = s - j;
    out[j] = (d == 0) ? n3 : (d == 1) ? n2 : (d == 2) ? n1 : (d == 3) ? n0 : 0.f;
  }
}

__device__ __forceinline__ u16x8 basis8_bf16(float xv, float g0, float invh) {
  float t[8];
  basis8_f32(xv, g0, invh, t);
  u16x8 o;
#pragma unroll
  for (int j = 0; j < 8; ++j) o[j] = f2bf(t[j]);
  return o;
}

// ---------------------------------------------------------------------------
// Prep kernels
// ---------------------------------------------------------------------------
__global__ __launch_bounds__(256) void prep_waug2(const float* __restrict__ bw,
                                                  const float* __restrict__ sw,
                                                  const float* __restrict__ sc,
                                                  unsigned short* __restrict__ Waug2) {
  int o = blockIdx.x;
  for (int k = threadIdx.x; k < 2304; k += 256) {
    float v;
    if (k < 256) {
      v = bw[o * 256 + k];
    } else {
      int idx = k - 256;
      int i = idx >> 3, g = idx & 7;
      v = sw[(o * 256 + i) * 8 + g] * sc[o * 256 + i];
    }
    int ks = k >> 6;
    int q = (k >> 3) & 7;
    int p = q ^ (o & 7);
    int e = k & 7;
    Waug2[(long)ks * 32768 + o * 64 + p * 8 + e] = f2bf(v);
  }
}

__global__ __launch_bounds__(256) void prep_whh(const float* __restrict__ w,
                                                unsigned short* __restrict__ hi,
                                                unsigned short* __restrict__ lo) {
  for (int i = blockIdx.x * 256 + threadIdx.x; i < 512 * 512; i += gridDim.x * 256) {
    float v = w[i];
    unsigned short h = f2bf(v);
    hi[i] = h;
    lo[i] = f2bf(v - bf2f(h));
  }
}

// i2h for x==0: parallel (one block per output, coalesced, LDS tree reduce).
__global__ __launch_bounds__(256) void prep_i2hz(const float* __restrict__ sw,
                                                 const float* __restrict__ sc,
                                                 const float* __restrict__ grd,
                                                 float* __restrict__ i2hz,
                                                 unsigned* __restrict__ cnt) {
  __shared__ float red[256];
  const int o = blockIdx.x;
  const int t = threadIdx.x;
  if (o == 0) {
    for (int i = t; i < 64 * 32; i += 256) cnt[i] = 0u;
  }
  float g0 = grd[0];
  float invh = 1.f / (grd[1] - grd[0]);
  float bs[8];
  basis8_f32(0.f, g0, invh, bs);
  const float* swrow = sw + ((long)o * 256 + t) * 8;
  float a = 0.f;
#pragma unroll
  for (int j = 0; j < 8; ++j) a += bs[j] * swrow[j];
  red[t] = a * sc[o * 256 + t];
  __syncthreads();
  for (int w = 128; w > 0; w >>= 1) {
    if (t < w) red[t] += red[t + w];
    __syncthreads();
  }
  if (t == 0) i2hz[o] = red[0];
}

// ---------------------------------------------------------------------------
// Phase A: i2h GEMM (R13-exact).  C(65536x512)=A_aug(65536x2304)@W_aug^T.
// 1024 blocks x 512 threads; tile 128m x 256n; LDS 48KB; pipelined A-compute.
// ---------------------------------------------------------------------------
__global__ __launch_bounds__(512, 4) void kan_i2h_gemm(const float* __restrict__ x,
                                                       const float* __restrict__ grd,
                                                       const unsigned short* __restrict__ Waug2,
                                                       float* __restrict__ hall) {
  __shared__ __align__(128) short Bs[256 * 64];   // 32 KB
  __shared__ __align__(128) short As[128 * 64];   // 16 KB

  const int bid = blockIdx.x;
  const int m0 = (bid >> 1) * 128;
  const int n0 = (bid & 1) * 256;
  const int tid = threadIdx.x;
  const int lane = tid & 63, wave = tid >> 6;   // 8 waves
  const int wr = wave >> 2, wc = wave & 3;      // 2 x 4
  const int colg = lane & 15, kgrp = lane >> 4;

  float g0 = grd[0];
  float invh = 1.f / (grd[1] - grd[0]);

  f32x4 acc[4][4] = {};

  const int arow = tid >> 2, apart = tid & 3;   // A: 128 rows x 4 parts x 16k
  const float* xrow = x + (long)(m0 + arow) * 256;
  const int aswz = arow & 7;
  short* const adst0 = (short*)((char*)As + arow * 128 + ((apart * 2) ^ aswz) * 16);
  short* const adst1 = (short*)((char*)As + arow * 128 + ((apart * 2 + 1) ^ aswz) * 16);

  auto computeA = [&](int ks, u16x8& d0, u16x8& d1) {
    int kA = ks * 64 + apart * 16;
    if (ks < 4) {
      const float* xs = xrow + kA;
      f32x4 v0 = *(const f32x4*)(xs);
      f32x4 v1 = *(const f32x4*)(xs + 4);
      f32x4 v2 = *(const f32x4*)(xs + 8);
      f32x4 v3 = *(const f32x4*)(xs + 12);
#pragma unroll
      for (int e = 0; e < 4; ++e) {
        d0[e] = f2bf(silu(v0[e]));
        d0[e + 4] = f2bf(silu(v1[e]));
        d1[e] = f2bf(silu(v2[e]));
        d1[e + 4] = f2bf(silu(v3[e]));
      }
    } else {
      int i0 = (kA - 256) >> 3;
      d0 = basis8_bf16(xrow[i0], g0, invh);
      d1 = basis8_bf16(xrow[i0 + 1], g0, invh);
    }
  };

  u16x8 ar0, ar1;
  computeA(0, ar0, ar1);

  for (int ks = 0; ks < 36; ++ks) {
    // B DMA: 32 KB linear copy (content pre-swizzled in Waug2)
    {
      const char* bsrc = (const char*)Waug2 + (long)ks * 65536 + n0 * 128 +
                         wave * 4096 + lane * 16;
      char* bdst = (char*)Bs + wave * 4096;
#pragma unroll
      for (int i = 0; i < 4; ++i)
        __builtin_amdgcn_global_load_lds(
            (const __attribute__((address_space(1))) unsigned int*)(bsrc + i * 1024),
            (__attribute__((address_space(3))) unsigned int*)(bdst + i * 1024), 16, 0, 0);
    }
    // A write (from pipelined regs)
    *(u16x8*)adst0 = ar0;
    *(u16x8*)adst1 = ar1;
    __syncthreads();   // drains gload_lds (vmcnt) + ds_write (lgkm)

    if (ks + 1 < 36) computeA(ks + 1, ar0, ar1);

#pragma unroll
    for (int kk = 0; kk < 2; ++kk) {
      const int q = kk * 4 + kgrp;
      s16x8 a[4], b[4];
#pragma unroll
      for (int i = 0; i < 4; ++i) {
        int ra = wr * 64 + i * 16 + colg;
        a[i] = *(const s16x8*)((const char*)As + ra * 128 + (q ^ (ra & 7)) * 16);
      }
#pragma unroll
      for (int j = 0; j < 4; ++j) {
        int rb = wc * 64 + j * 16 + colg;   // local row; n0%8==0 -> rb&7 == o&7
        b[j] = *(const s16x8*)((const char*)Bs + rb * 128 + (q ^ (rb & 7)) * 16);
      }
#pragma unroll
      for (int i = 0; i < 4; ++i)
#pragma unroll
        for (int j = 0; j < 4; ++j)
          acc[i][j] = __builtin_amdgcn_mfma_f32_16x16x32_bf16(a[i], b[j], acc[i][j], 0, 0, 0);
    }
    __syncthreads();
  }

  const int c0 = n0 + wc * 64;
#pragma unroll
  for (int i = 0; i < 4; ++i) {
    int mbase = m0 + wr * 64 + i * 16 + (kgrp << 2);
#pragma unroll
    for (int r = 0; r < 4; ++r) {
      int m = mbase + r;
      int bb = m >> 6, tt = m & 63;
      float* orow = hall + (long)bb * HALL_BSTRIDE + (long)tt * HALL_TSTRIDE + c0;
#pragma unroll
      for (int j = 0; j < 4; ++j) orow[j * 16 + colg] = acc[i][j][r];
    }
  }
}

// ---------------------------------------------------------------------------
// Phase B: VGPR-pinned-weight recurrence.  256 blocks x 512 threads
// (1 block/CU — the ~230 unified-VGPR budget caps at 8 waves/CU), block =
// 16 batch rows x 128 cols, 8 waves x 16 cols, weights pinned via asm.
// R16 change: own-col LDS shortcut — after the post-store barrier (all
// waves are past their MFMA reads, so no LDS race), each thread writes its
// own 4 h values into hHb/hLb (2B swizzled, f32-exact = bit-identical),
// overlapping the atomic+spin; refill skips jj==cg (25% less gated reload).
// ---------------------------------------------------------------------------
__device__ __forceinline__ void pack_write_h(f32x4 v, int rr, int c16,
                                             char* hHb, char* hLb) {
  unsigned h0 = f2bf(v[0]), h1 = f2bf(v[1]), h2 = f2bf(v[2]), h3 = f2bf(v[3]);
  unsigned l0 = f2bf(v[0] - bf2f((unsigned short)h0));
  unsigned l1 = f2bf(v[1] - bf2f((unsigned short)h1));
  unsigned l2 = f2bf(v[2] - bf2f((unsigned short)h2));
  unsigned l3 = f2bf(v[3] - bf2f((unsigned short)h3));
  u32x2 hw, lw;
  hw[0] = h0 | (h1 << 16); hw[1] = h2 | (h3 << 16);
  lw[0] = l0 | (l1 << 16); lw[1] = l2 | (l3 << 16);
  int byte = (rr * 1024 + c16 * 8) ^ ((rr & 7) << 4);
  *(u32x2*)(hHb + byte) = hw;
  *(u32x2*)(hLb + byte) = lw;
}

__global__ __launch_bounds__(512, 2) void rnn_persist(
    const unsigned short* __restrict__ WhhHi,
    const unsigned short* __restrict__ WhhLo,
    const float* __restrict__ i2hz,
    const float* __restrict__ h2hb,
    const float* __restrict__ h0,
    float* __restrict__ hall,
    unsigned* __restrict__ cnt) {
  __shared__ __align__(16) char hHb[16 * 1024];
  __shared__ __align__(16) char hLb[16 * 1024];

  const int tid = threadIdx.x;
  const int lane = tid & 63;
  const int wave = tid >> 6;            // 0..7
  const int bid = blockIdx.x;
  // XCD-local grouping: the 4 col-siblings of a batch-group share bid%8
  const int xcd = bid & 7;              // XCD (round-robin dispatch)
  const int j = bid >> 3;               // 0..31
  const int cg = j & 3;                 // col-group
  const int g = xcd * 8 + (j >> 2);     // batch-group 0..63
  const int m0 = g * 16;                // batch rows
  const int colg = lane & 15;
  const int kgrp = lane >> 4;           // 0..3
  const int o = cg * 128 + wave * 16 + colg;   // this lane's output col
  const int aswz = (colg & 7) << 4;

  // ---- pin this wave's weight slice in VGPRs (asm: not rematerializable) --
  s16x8 wh[16], wl[16];
#pragma unroll
  for (int kk = 0; kk < 16; ++kk) {
    const unsigned short* ph = WhhHi + (long)o * 512 + kk * 32 + kgrp * 8;
    const unsigned short* pl = WhhLo + (long)o * 512 + kk * 32 + kgrp * 8;
    asm volatile("global_load_dwordx4 %0, %1, off" : "=v"(wh[kk]) : "v"(ph));
    asm volatile("global_load_dwordx4 %0, %1, off" : "=v"(wl[kk]) : "v"(pl));
  }
  const float bias = h2hb[o];
  const float i2z = i2hz[o];
  asm volatile("s_waitcnt vmcnt(0)" ::: "memory");
  __builtin_amdgcn_sched_barrier(0);

  // ---- prologue: h0 -> LDS (hi/lo, swizzled) ----
  {
    const int rr = tid >> 5, cc = tid & 31;
#pragma unroll
    for (int jj = 0; jj < 4; ++jj) {
      int c16 = cc + jj * 32;
      f32x4 v = *(const f32x4*)(h0 + (long)(m0 + rr) * 512 + c16 * 4);
      pack_write_h(v, rr, c16, hHb, hLb);
    }
  }
  __syncthreads();

  for (int T = 0; T < 80; ++T) {
    // issue i2h coherent loads early (land under MFMA loop)
    float i2v[4];
    if (T < 64) {
#pragma unroll
      for (int r = 0; r < 4; ++r) {
        const float* p = hall + (long)(m0 + kgrp * 4 + r) * HALL_BSTRIDE +
                         (long)T * HALL_TSTRIDE + o;
        asm volatile("global_load_dword %0, %1, off sc0 sc1" : "=v"(i2v[r]) : "v"(p));
      }
    }

    f32x4 aA = {}, aB = {}, aC = {};
#pragma unroll
    for (int kk = 0; kk < 16; ++kk) {
      int abyte = (colg * 1024 + kk * 64 + kgrp * 16) ^ aswz;
      s16x8 ah = *(const s16x8*)(hHb + abyte);
      s16x8 al = *(const s16x8*)(hLb + abyte);
      aA = __builtin_amdgcn_mfma_f32_16x16x32_bf16(ah, wh[kk], aA, 0, 0, 0);
      aB = __builtin_amdgcn_mfma_f32_16x16x32_bf16(ah, wl[kk], aB, 0, 0, 0);
      aC = __builtin_amdgcn_mfma_f32_16x16x32_bf16(al, wh[kk], aC, 0, 0, 0);
    }

    if (T < 64) {
      asm volatile("s_waitcnt vmcnt(0)" ::: "memory");
      __builtin_amdgcn_sched_barrier(0);
    } else {
#pragma unroll
      for (int r = 0; r < 4; ++r) i2v[r] = i2z;
    }

    // epilogue: tanh + coherent store of h into hall (the exchange medium)
    float hv[4];
#pragma unroll
    for (int r = 0; r < 4; ++r) {
      float pre = aA[r] + aB[r] + aC[r] + i2v[r] + bias;
      float h = tanh_fast(pre);
      hv[r] = h;
      float* p = hall + (long)(m0 + kgrp * 4 + r) * HALL_BSTRIDE +
                 (long)T * HALL_TSTRIDE + o;
      asm volatile("global_store_dword %0, %1, off sc0 sc1" :: "v"(p), "v"(h) : "memory");
    }

    if (T == 79) break;

    asm volatile("s_waitcnt vmcnt(0)" ::: "memory");
    __syncthreads();   // all stores done AND all waves past their MFMA reads

    // own-col LDS shortcut (overlaps tid0's atomic+spin; no reader until
    // the next barrier)
#pragma unroll
    for (int r = 0; r < 4; ++r) {
      int lrow = kgrp * 4 + r;
      int byte = (lrow * 1024 + o * 2) ^ ((lrow & 7) << 4);
      unsigned short hh = f2bf(hv[r]);
      *(unsigned short*)(hHb + byte) = hh;
      *(unsigned short*)(hLb + byte) = f2bf(hv[r] - bf2f(hh));
    }

    if (tid == 0) {
      __hip_atomic_fetch_add(&cnt[g * 32], 1u, __ATOMIC_RELAXED,
                             __HIP_MEMORY_SCOPE_AGENT);
      unsigned tgt = 4u * (unsigned)(T + 1);
      while (__hip_atomic_load(&cnt[g * 32], __ATOMIC_RELAXED,
                               __HIP_MEMORY_SCOPE_AGENT) < tgt)
        __builtin_amdgcn_s_sleep(2);
    }
    __syncthreads();

    // refill: coherent loads of SIBLING cols of h_T (3/4 of 16x512) -> LDS
    {
      const int rr = tid >> 5, cc = tid & 31;
      const float* src = hall + (long)(m0 + rr) * HALL_BSTRIDE + (long)T * HALL_TSTRIDE;
      f32x4 v[4];
#pragma unroll
      for (int jj = 0; jj < 4; ++jj) {
        if (jj == cg) continue;          // own cols already in LDS
        const float* p = src + (cc + jj * 32) * 4;
        asm volatile("global_load_dwordx4 %0, %1, off sc0 sc1" : "=v"(v[jj]) : "v"(p));
      }
      asm volatile("s_waitcnt vmcnt(0)" ::: "memory");
      __builtin_amdgcn_sched_barrier(0);
#pragma unroll
      for (int jj = 0; jj < 4; ++jj) {
        if (jj == cg) continue;
        pack_write_h(v[jj], rr, cc + jj * 32, hHb, hLb);
      }
    }
    __syncthreads();
  }
}

// ---------------------------------------------------------------------------
// y_pred[b][ty] = dot(h_all[b][64+ty][:], fc_w) + fc_b   (one wave per (b,ty))
// ---------------------------------------------------------------------------
__global__ __launch_bounds__(256) void y_final(const float* __restrict__ hall,
                                               const float* __restrict__ fcw,
                                               const float* __restrict__ fcb,
                                               float* __restrict__ y) {
  int gw = (blockIdx.x * 256 + threadIdx.x) >> 6;
  int lane = threadIdx.x & 63;
  int bb = gw >> 4, ty = gw & 15;
  const float* hrow = hall + (long)bb * HALL_BSTRIDE + (long)(64 + ty) * HALL_TSTRIDE;
  float s = 0.f;
#pragma unroll
  for (int c = 0; c < 8; ++c) s += hrow[lane + c * 64] * fcw[lane + c * 64];
#pragma unroll
  for (int off = 32; off > 0; off >>= 1) s += __shfl_xor(s, off);
  if (lane == 0) y[bb * 16 + ty] = s + fcb[0];
}

// ---------------------------------------------------------------------------
extern "C" void kernel_launch(void* const* d_in, const int* in_sizes, int n_in,
                              void* d_out, int out_size, void* d_ws, size_t ws_size,
                              hipStream_t stream) {
  (void)in_sizes; (void)n_in; (void)out_size; (void)ws_size;
  const float* x   = (const float*)d_in[0];
  const float* h0  = (const float*)d_in[1];
  const float* grd = (const float*)d_in[2];
  const float* bw  = (const float*)d_in[3];
  const float* sw  = (const float*)d_in[4];
  const float* sc  = (const float*)d_in[5];
  const float* whh = (const float*)d_in[6];
  const float* hbb = (const float*)d_in[7];
  const float* fcw = (const float*)d_in[8];
  const float* fcb = (const float*)d_in[9];

  float* out = (float*)d_out;
  float* ypred = out;
  float* hall = out + 1024 * 16;

  char* ws = (char*)d_ws;
  unsigned short* Waug2 = (unsigned short*)(ws);                 // 2359296 B
  unsigned short* WhhHi = (unsigned short*)(ws + 2359296);       // 524288 B
  unsigned short* WhhLo = (unsigned short*)(ws + 2883584);       // 524288 B
  float*          i2hz  = (float*)(ws + 3407872);                // 2048 B
  unsigned*       cnt   = (unsigned*)(ws + 3409920);             // 8192 B

  prep_waug2<<<512, 256, 0, stream>>>(bw, sw, sc, Waug2);
  prep_whh<<<512, 256, 0, stream>>>(whh, WhhHi, WhhLo);
  prep_i2hz<<<512, 256, 0, stream>>>(sw, sc, grd, i2hz, cnt);
  kan_i2h_gemm<<<1024, 512, 0, stream>>>(x, grd, Waug2, hall);
  rnn_persist<<<256, 512, 0, stream>>>(WhhHi, WhhLo, i2hz, hbb, h0, hall, cnt);
  y_final<<<4096, 256, 0, stream>>>(hall, fcw, fcb, ypred);
}